// Round 8
// baseline (278.562 us; speedup 1.0000x reference)
//
#include <hip/hip_runtime.h>

typedef _Float16 f16;
typedef _Float16 f16x8 __attribute__((ext_vector_type(8)));
typedef float f32x4 __attribute__((ext_vector_type(4)));
typedef unsigned short u16;
typedef unsigned int u32;
typedef u32 u32x4 __attribute__((ext_vector_type(4)));

#define QMAX 32767.0f

// ---- workspace layout (bytes); total = 35,801,088 ----
#define WS_SLOTS    0u         // 4 x u32 amax slots: x, h1, h2, h3
#define WS_BN1_INV  256u       // 256 f32
#define WS_BN1_BETA 1280u
#define WS_BN2_INV  2304u
#define WS_BN2_BETA 3328u
#define WS_BN3_INV  4352u      // 1024 f32
#define WS_BN3_BETA 8448u
#define WS_PEG_B    12544u     // 256 f32
#define WS_PEGQ     13568u     // [9][256] f16
#define WS_W1Q      18432u     // [256 co][1024 ci] f16
#define WS_W3Q      542720u    // [1024 co][256 ci] f16
#define WS_W2Q      1067008u   // [9 tap][256 co][256 ci] f16
#define WS_H1T      2246656u   // [32768 p][256 c] f16 (reused as h3T)
#define WS_H2T      19023872u  // [32768 p][256 c] f16

__device__ __forceinline__ int badf(float f){  // Inf or NaN, fast-math-immune
  union { float f; u32 u; } c; c.f = f;
  return (c.u & 0x7f800000u) == 0x7f800000u;
}
// read amax slot -> guaranteed finite positive scale base
__device__ __forceinline__ float slot_amax(const u32* slots, int i){
  union { u32 u; float f; } c; c.u = slots[i];
  if ((c.u & 0x7f800000u) == 0x7f800000u) c.f = 1.0f;  // Inf/NaN -> 1.0
  float a = c.f;
  a = fminf(fmaxf(a, 1e-12f), 1e8f);
  return a;
}
// symmetric 16-bit fake-quant, Inf-safe (clamped to +-QMAX)
__device__ __forceinline__ float fq(float v, float is, float s){
  float t = v * is;
  t = fminf(fmaxf(t, -QMAX), QMAX);   // kills +-Inf; finite in, finite out
  return rintf(t) * s;
}
// DeepShift pow2 weight quant: sign(w)*2^clip(round(log2|w|), -14, 0)
__device__ __forceinline__ float qpow2(float w){
  float a = fabsf(w) + 1e-20f;
  float p = rintf(log2f(a));
  p = fminf(fmaxf(p, -14.0f), 0.0f);
  float m = exp2f(p);
  return (w > 0.0f) ? m : ((w < 0.0f) ? -m : 0.0f);
}
// LDS 16B-slot swizzle: uniform bank spread for [row][64B] tiles
#define SWZ(row, slot) ((((slot) ^ ((row) >> 1) ^ ((row) >> 3))) & 3)

__device__ __forceinline__ float wave_max(float v){
  #pragma unroll
  for (int off = 32; off > 0; off >>= 1) v = fmaxf(v, __shfl_xor(v, off));
  return v;
}
// block-level amax -> ONE device atomic per block
__device__ __forceinline__ void block_amax(float mx, u32* slot, float* red,
                                           int tid, int nw){
  mx = wave_max(mx);
  if ((tid & 63) == 0) red[tid >> 6] = mx;
  __syncthreads();
  if (tid == 0){
    float m = red[0];
    #pragma unroll
    for (int i = 1; i < 8; ++i) if (i < nw) m = fmaxf(m, red[i]);
    atomicMax(slot, __float_as_uint(m));
  }
}

// shared MFMA inner step (128x128 tile kernels): As at lds[0..8192), Bs at [8192..16384)
__device__ __forceinline__ void mfma_step(const char* lds, int wm, int wn,
                                          int lr, int lg, f32x4 acc[4][4]){
  f16x8 a[4], bb[4];
  #pragma unroll
  for (int mf = 0; mf < 4; ++mf){
    int row = (wm << 6) + (mf << 4) + lr;
    a[mf] = *(const f16x8*)(lds + (row << 6) + (SWZ(row, lg) << 4));
  }
  #pragma unroll
  for (int nf = 0; nf < 4; ++nf){
    int row = (wn << 6) + (nf << 4) + lr;
    bb[nf] = *(const f16x8*)(lds + 8192 + (row << 6) + (SWZ(row, lg) << 4));
  }
  #pragma unroll
  for (int mf = 0; mf < 4; ++mf)
    #pragma unroll
    for (int nf = 0; nf < 4; ++nf)
      acc[mf][nf] = __builtin_amdgcn_mfma_f32_16x16x32_f16(a[mf], bb[nf], acc[mf][nf], 0, 0, 0);
}

// ---- prep: quantize all weights to f16 pow2, precompute BN affine ----
__global__ __launch_bounds__(256) void prep_kernel(
    const float* __restrict__ w1, const float* __restrict__ pegw, const float* __restrict__ pegb,
    const float* __restrict__ w2, const float* __restrict__ w3,
    const float* g1, const float* b1, const float* m1, const float* v1,
    const float* g2, const float* b2, const float* m2, const float* v2,
    const float* g3, const float* b3, const float* m3, const float* v3,
    char* ws){
  int i = blockIdx.x * 256 + threadIdx.x;
  if (i < 262144){ ((f16*)(ws + WS_W1Q))[i] = (f16)qpow2(w1[i]); return; }
  i -= 262144;
  if (i < 589824){ // repack OIHW -> [tap][co][ci]
    int tap = i >> 16, rem = i & 65535;
    int co = rem >> 8, ci = rem & 255;
    ((f16*)(ws + WS_W2Q))[i] = (f16)qpow2(w2[(((co << 8) + ci) * 9) + tap]);
    return;
  }
  i -= 589824;
  if (i < 262144){ ((f16*)(ws + WS_W3Q))[i] = (f16)qpow2(w3[i]); return; }
  i -= 262144;
  if (i < 2304){ // [c][tap] -> [tap][c]
    int tap = i >> 8, c = i & 255;
    ((f16*)(ws + WS_PEGQ))[i] = (f16)qpow2(pegw[c * 9 + tap]);
    return;
  }
  i -= 2304;
  if (i < 256){ ((float*)(ws + WS_PEG_B))[i] = pegb[i]; return; }
  i -= 256;
  if (i < 256){
    float inv = g1[i] / sqrtf(v1[i] + 1e-5f);
    ((float*)(ws + WS_BN1_INV))[i] = inv;
    ((float*)(ws + WS_BN1_BETA))[i] = b1[i] - m1[i] * inv;
    return;
  }
  i -= 256;
  if (i < 256){
    float inv = g2[i] / sqrtf(v2[i] + 1e-5f);
    ((float*)(ws + WS_BN2_INV))[i] = inv;
    ((float*)(ws + WS_BN2_BETA))[i] = b2[i] - m2[i] * inv;
    return;
  }
  i -= 256;
  if (i < 1024){
    float inv = g3[i] / sqrtf(v3[i] + 1e-5f);
    ((float*)(ws + WS_BN3_INV))[i] = inv;
    ((float*)(ws + WS_BN3_BETA))[i] = b3[i] - m3[i] * inv;
  }
}

// ---- global amax(|x|) over 33.5M f32 ----
__global__ __launch_bounds__(256) void amax_x_kernel(const float* __restrict__ x, u32* slots){
  __shared__ float red[8];
  float m = 0.0f;
  int stride = gridDim.x * blockDim.x;
  for (int v = blockIdx.x * blockDim.x + threadIdx.x; v < 8388608; v += stride){
    f32x4 d = ((const f32x4*)x)[v];
    #pragma unroll
    for (int j = 0; j < 4; ++j) m = fmaxf(m, fabsf(d[j]));
  }
  block_amax(m, &slots[0], red, threadIdx.x, 4);
}

// ---- conv1: 1x1 1024->256. M=pixels(128-tile), N=co(128-tile), K=ci=1024. ----
__global__ __launch_bounds__(256) void conv1_kernel(const float* __restrict__ x, char* ws){
  __shared__ __align__(16) char lds[16384];
  __shared__ float red[8];
  const f16* w1q = (const f16*)(ws + WS_W1Q);
  f16* h1T = (f16*)(ws + WS_H1T);
  u32* slots = (u32*)(ws + WS_SLOTS);
  float am = slot_amax(slots, 0);
  float s0 = am / QMAX, is0 = QMAX / am;

  int tid = threadIdx.x, bid = blockIdx.x;
  int b = bid >> 4, m0 = ((bid >> 1) & 7) << 7, n0 = (bid & 1) << 7;
  int l = tid & 63, wid = tid >> 6, wm = wid >> 1, wn = wid & 1;
  int lr = l & 15, lg = l >> 4;
  f32x4 acc[4][4] = {};

  int pblk = tid & 15;   // 16 pixel-blocks of 8
  int cil  = tid >> 4;   // 16 ci rows per pass

  for (int ks = 0; ks < 32; ++ks){
    int k0 = ks << 5;
    // stage A: x[b][k0+ci][m0 + p] -> As[p][ci] (transpose + quant)
    #pragma unroll
    for (int i = 0; i < 2; ++i){
      int ci = cil + (i << 4);
      const float* src = x + (((size_t)(b << 10) + k0 + ci) << 10) + m0 + (pblk << 3);
      f32x4 d0 = *(const f32x4*)src;
      f32x4 d1 = *(const f32x4*)(src + 4);
      #pragma unroll
      for (int j = 0; j < 8; ++j){
        float xv = (j < 4) ? d0[j] : d1[j - 4];
        float q = fq(xv, is0, s0);
        int row = (pblk << 3) + j;
        *(f16*)(lds + (row << 6) + (SWZ(row, ci >> 3) << 4) + ((ci & 7) << 1)) = (f16)q;
      }
    }
    // stage B: w1q[n0+row][k0 + slot*8] copy
    #pragma unroll
    for (int i = 0; i < 2; ++i){
      int s = tid + (i << 8);
      int row = s >> 2, slot = s & 3;
      u32x4 d = *(const u32x4*)(w1q + ((size_t)(n0 + row) << 10) + k0 + (slot << 3));
      *(u32x4*)(lds + 8192 + (row << 6) + (SWZ(row, slot) << 4)) = d;
    }
    __syncthreads();
    mfma_step(lds, wm, wn, lr, lg, acc);
    __syncthreads();
  }

  float mx = 0.0f;
  #pragma unroll
  for (int mf = 0; mf < 4; ++mf){
    int p0 = m0 + (wm << 6) + (mf << 4) + (lg << 2);
    size_t base = ((size_t)(b << 10) + p0) << 8;
    #pragma unroll
    for (int nf = 0; nf < 4; ++nf){
      int co = n0 + (wn << 6) + (nf << 4) + lr;
      #pragma unroll
      for (int r = 0; r < 4; ++r){
        float f = acc[mf][nf][r];
        mx = fmaxf(mx, fabsf(f));
        h1T[base + ((size_t)r << 8) + co] = (f16)f;
      }
    }
  }
  block_amax(mx, &slots[1], red, tid, 4);
}

// ---- PEG: depthwise 3x3, block = one (batch,row), quantize once in LDS ----
__global__ __launch_bounds__(256) void peg_kernel(char* ws){
  __shared__ __align__(16) f16 tile[3][32][256];   // 48 KB
  __shared__ float red[8];
  const f16* h1T = (const f16*)(ws + WS_H1T);
  const f16* pegq = (const f16*)(ws + WS_PEGQ);
  const float* pb  = (const float*)(ws + WS_PEG_B);
  const float* inv1 = (const float*)(ws + WS_BN1_INV);
  const float* bt1  = (const float*)(ws + WS_BN1_BETA);
  f16* h2T = (f16*)(ws + WS_H2T);
  u32* slots = (u32*)(ws + WS_SLOTS);
  float am = slot_amax(slots, 1);
  float s1 = am / QMAX, is1 = QMAX / am;

  int tid = threadIdx.x;
  int b = blockIdx.x >> 5, h = blockIdx.x & 31;

  // stage rows h-1, h, h+1 (quantized); zeros outside image
  #pragma unroll
  for (int r = 0; r < 3; ++r){
    int hh = h + r - 1;
    #pragma unroll
    for (int i = 0; i < 4; ++i){
      int chunk = tid + (i << 8);          // 0..1023
      int px = chunk >> 5, cg = chunk & 31;
      u32x4 d = {0u, 0u, 0u, 0u};
      if ((u32)hh < 32u)
        d = *(const u32x4*)(h1T + (((size_t)(b << 10) + (hh << 5) + px) << 8) + (cg << 3));
      f16x8 hv = __builtin_bit_cast(f16x8, d);
      f16x8 qv;
      #pragma unroll
      for (int j = 0; j < 8; ++j) qv[j] = (f16)fq((float)hv[j], is1, s1);
      *(f16x8*)(&tile[r][px][cg << 3]) = qv;
    }
  }
  __syncthreads();

  int c0 = (tid & 31) << 3;   // 8 channels
  int q  = tid >> 5;          // pixel quad: px = 4q..4q+3
  float acc[4][8];
  #pragma unroll
  for (int i = 0; i < 4; ++i)
    #pragma unroll
    for (int j = 0; j < 8; ++j) acc[i][j] = pb[c0 + j];

  #pragma unroll
  for (int ky = 0; ky < 3; ++ky){
    #pragma unroll
    for (int kx = 0; kx < 3; ++kx){
      f16x8 wv = *(const f16x8*)(pegq + ((ky * 3 + kx) << 8) + c0);
      #pragma unroll
      for (int i = 0; i < 4; ++i){
        int ww = (q << 2) + i + kx - 1;
        if ((u32)ww < 32u){
          f16x8 v = *(const f16x8*)(&tile[ky][ww][c0]);
          #pragma unroll
          for (int j = 0; j < 8; ++j) acc[i][j] += (float)v[j] * (float)wv[j];
        }
      }
    }
  }

  f32x4 iv0 = *(const f32x4*)(inv1 + c0), iv1 = *(const f32x4*)(inv1 + c0 + 4);
  f32x4 bt0 = *(const f32x4*)(bt1 + c0),  bt1v = *(const f32x4*)(bt1 + c0 + 4);
  float mx = 0.0f;
  #pragma unroll
  for (int i = 0; i < 4; ++i){
    f16x8 o;
    #pragma unroll
    for (int j = 0; j < 8; ++j){
      float ivj = (j < 4) ? iv0[j] : iv1[j - 4];
      float btj = (j < 4) ? bt0[j] : bt1v[j - 4];
      float f = fmaxf(acc[i][j] * ivj + btj, 0.0f);
      mx = fmaxf(mx, f);
      o[j] = (f16)f;
    }
    int p = (h << 5) + (q << 2) + i;
    *(f16x8*)(h2T + (((size_t)(b << 10) + p) << 8) + c0) = o;
  }
  block_amax(mx, &slots[2], red, tid, 4);
}

// ---- conv2: 3x3 256->256. Block = 128 px x full 256 co, 8 waves; A staged once ----
__global__ __launch_bounds__(512) void conv2_kernel(char* ws){
  __shared__ __align__(16) char lds[104448 + 32768];  // A(6*34*512B) + B dbuf(2*16KB)
  __shared__ float red[8];
  const f16* h2T = (const f16*)(ws + WS_H2T);
  const f16* w2q = (const f16*)(ws + WS_W2Q);
  const float* inv2 = (const float*)(ws + WS_BN2_INV);
  const float* bt2  = (const float*)(ws + WS_BN2_BETA);
  f16* h3T = (f16*)(ws + WS_H1T);
  u32* slots = (u32*)(ws + WS_SLOTS);
  float am = slot_amax(slots, 2);
  float s2 = am / QMAX, is2 = QMAX / am;

  int tid = threadIdx.x, bid = blockIdx.x;
  int b = bid >> 3, mt = bid & 7;
  int h0 = mt << 2;             // first image row of tile
  int m0 = mt << 7;             // first pixel of tile
  int l = tid & 63, wid = tid >> 6, wm = wid >> 2, wn = wid & 3;
  int lr = l & 15, lg = l >> 4;
  char* A = lds;
  char* B0 = lds + 104448;
  char* B1 = lds + 104448 + 16384;

  // stage A once: tile[r][cc][ci], r=0..5 <-> image rows h0-1..h0+4,
  // cc=0..33 <-> cols -1..32 (zero halo). swizzled slot = slot ^ ((cc&7)<<2).
  for (int chunk = tid; chunk < 6528; chunk += 512){
    int r = chunk / 1088;                 // 1088 = 34*32
    int rem = chunk - r * 1088;
    int cc = rem >> 5, slot = rem & 31;
    int hh = h0 - 1 + r, wwp = cc - 1;
    u32x4 d = {0u, 0u, 0u, 0u};
    if ((u32)hh < 32u && (u32)wwp < 32u)
      d = *(const u32x4*)(h2T + (((size_t)(b << 10) + (hh << 5) + wwp) << 8) + (slot << 3));
    f16x8 hv = __builtin_bit_cast(f16x8, d);
    f16x8 qv;
    #pragma unroll
    for (int j = 0; j < 8; ++j) qv[j] = (f16)fq((float)hv[j], is2, s2);
    int sw = slot ^ ((cc & 7) << 2);
    *(f16x8*)(A + ((r * 34 + cc) << 9) + (sw << 4)) = qv;
  }
  // stage B for step 0 (tap 0, ks 0)
  #pragma unroll
  for (int i = 0; i < 2; ++i){
    int chunk = tid + (i << 9);
    int co = chunk >> 2, slot = chunk & 3;
    u32x4 d = *(const u32x4*)(w2q + (co << 8) + (slot << 3));
    *(u32x4*)(B0 + (co << 6) + (SWZ(co, slot) << 4)) = d;
  }
  __syncthreads();

  f32x4 acc[4][4] = {};
  for (int tap = 0; tap < 9; ++tap){
    int dy = tap / 3 - 1, dx = tap % 3 - 1;
    // hoist per-tap A fragment bases (each mf-frag's 16 lanes share one image row)
    int rowbase[4], key[4];
    #pragma unroll
    for (int mf = 0; mf < 4; ++mf){
      int p = (wm << 6) + (mf << 4) + lr;
      int rr = (p >> 5) + dy + 1;
      int cc = (p & 31) + dx + 1;
      rowbase[mf] = ((rr * 34 + cc) << 9) + (lg << 4);
      key[mf] = cc & 7;
    }
    #pragma unroll 2
    for (int ks = 0; ks < 8; ++ks){
      int t = (tap << 3) + ks;
      // early-issue next B tile global loads into regs
      u32x4 st[2];
      int have = (t < 71);
      int t1 = t + 1, wtap = t1 >> 3, wks = t1 & 7;
      const f16* srcb = w2q + wtap * 65536 + (wks << 5);
      if (have){
        #pragma unroll
        for (int i = 0; i < 2; ++i){
          int chunk = tid + (i << 9);
          int co = chunk >> 2, slot = chunk & 3;
          st[i] = *(const u32x4*)(srcb + (co << 8) + (slot << 3));
        }
      }
      // fragments
      const char* bs = (t & 1) ? B1 : B0;
      f16x8 a[4], bb[4];
      #pragma unroll
      for (int mf = 0; mf < 4; ++mf)
        a[mf] = *(const f16x8*)(A + rowbase[mf] + ((ks ^ key[mf]) << 6));
      #pragma unroll
      for (int nf = 0; nf < 4; ++nf){
        int row = (wn << 6) + (nf << 4) + lr;
        bb[nf] = *(const f16x8*)(bs + (row << 6) + (SWZ(row, lg) << 4));
      }
      #pragma unroll
      for (int mf = 0; mf < 4; ++mf)
        #pragma unroll
        for (int nf = 0; nf < 4; ++nf)
          acc[mf][nf] = __builtin_amdgcn_mfma_f32_16x16x32_f16(a[mf], bb[nf], acc[mf][nf], 0, 0, 0);
      // late write of staged B
      if (have){
        char* bd = (t1 & 1) ? B1 : B0;
        #pragma unroll
        for (int i = 0; i < 2; ++i){
          int chunk = tid + (i << 9);
          int co = chunk >> 2, slot = chunk & 3;
          *(u32x4*)(bd + (co << 6) + (SWZ(co, slot) << 4)) = st[i];
        }
      }
      __syncthreads();
    }
  }

  float mx = 0.0f;
  #pragma unroll
  for (int mf = 0; mf < 4; ++mf){
    int p0 = m0 + (wm << 6) + (mf << 4) + (lg << 2);
    size_t base = ((size_t)(b << 10) + p0) << 8;
    #pragma unroll
    for (int nf = 0; nf < 4; ++nf){
      int co = (wn << 6) + (nf << 4) + lr;
      float iv = inv2[co], bt = bt2[co];
      #pragma unroll
      for (int r = 0; r < 4; ++r){
        float f = fmaxf(acc[mf][nf][r] * iv + bt, 0.0f);
        mx = fmaxf(mx, f);
        h3T[base + ((size_t)r << 8) + co] = (f16)f;
      }
    }
  }
  block_amax(mx, &slots[3], red, tid, 8);
}

// ---- conv3: 1x1 256->1024. BARRIER-FREE: no LDS — MFMA fragments loaded
// directly from global (per-lane addressing matches fragment layout; L2
// serves the 2x reuse). Full software pipelining across K; x-residual reads
// overlap tail MFMAs. bn3 + residual + relu -> NCHW f32. ----
__global__ __launch_bounds__(256) void conv3_kernel(const float* __restrict__ x,
                                                    float* __restrict__ out, char* ws){
  const f16* w3q = (const f16*)(ws + WS_W3Q);
  const f16* h3T = (const f16*)(ws + WS_H1T);
  const float* inv3 = (const float*)(ws + WS_BN3_INV);
  const float* bt3  = (const float*)(ws + WS_BN3_BETA);
  u32* slots = (u32*)(ws + WS_SLOTS);
  float am = slot_amax(slots, 3);
  float s3 = am / QMAX, is3 = QMAX / am;

  int tid = threadIdx.x, bid = blockIdx.x;
  int b = bid >> 6, m0 = ((bid >> 3) & 7) << 7, n0 = (bid & 7) << 7;
  int l = tid & 63, wid = tid >> 6, wm = wid >> 1, wn = wid & 1;
  int lr = l & 15, lg = l >> 4;
  f32x4 acc[4][4] = {};

  // per-lane fragment bases: lane reads its own f16x8 directly
  const f16* aBase = w3q + (((size_t)(m0 + (wm << 6) + lr)) << 8) + (lg << 3);
  const f16* bBase = h3T + (((size_t)(b << 10) + n0 + (wn << 6) + lr) << 8) + (lg << 3);

  #pragma unroll
  for (int ks = 0; ks < 8; ++ks){
    int k0 = ks << 5;
    f16x8 a[4], bq[4];
    #pragma unroll
    for (int mf = 0; mf < 4; ++mf)
      a[mf] = *(const f16x8*)(aBase + ((size_t)(mf << 4) << 8) + k0);
    #pragma unroll
    for (int nf = 0; nf < 4; ++nf){
      f16x8 hv = *(const f16x8*)(bBase + ((size_t)(nf << 4) << 8) + k0);
      #pragma unroll
      for (int j = 0; j < 8; ++j) bq[nf][j] = (f16)fq((float)hv[j], is3, s3);
    }
    #pragma unroll
    for (int mf = 0; mf < 4; ++mf)
      #pragma unroll
      for (int nf = 0; nf < 4; ++nf)
        acc[mf][nf] = __builtin_amdgcn_mfma_f32_16x16x32_f16(a[mf], bq[nf], acc[mf][nf], 0, 0, 0);
  }

  // epilogue: per-mf chunks (16 x-loads batched, then compute+store)
  #pragma unroll
  for (int mf = 0; mf < 4; ++mf){
    int co0 = m0 + (wm << 6) + (mf << 4) + (lg << 2);
    f32x4 iv = *(const f32x4*)(inv3 + co0);
    f32x4 bt = *(const f32x4*)(bt3 + co0);
    float xr[16];
    #pragma unroll
    for (int nf = 0; nf < 4; ++nf){
      int p = n0 + (wn << 6) + (nf << 4) + lr;
      #pragma unroll
      for (int r = 0; r < 4; ++r)
        xr[(nf << 2) + r] = x[(((size_t)(b << 10) + co0 + r) << 10) + p];
    }
    #pragma unroll
    for (int nf = 0; nf < 4; ++nf){
      int p = n0 + (wn << 6) + (nf << 4) + lr;
      #pragma unroll
      for (int r = 0; r < 4; ++r){
        size_t idx = (((size_t)(b << 10) + co0 + r) << 10) + p;
        float z = acc[mf][nf][r] * iv[r] + bt[r] + xr[(nf << 2) + r];
        float rr = fmaxf(z, 0.0f);
        if (badf(z)) rr = 512.0f;   // NaN/Inf beacon: visible in absmax
        out[idx] = rr;
      }
    }
  }
}

extern "C" void kernel_launch(void* const* d_in, const int* in_sizes, int n_in,
                              void* d_out, int out_size, void* d_ws, size_t ws_size,
                              hipStream_t stream){
  const float* x    = (const float*)d_in[0];
  const float* w1   = (const float*)d_in[1];
  const float* pegw = (const float*)d_in[2];
  const float* pegb = (const float*)d_in[3];
  const float* w2   = (const float*)d_in[4];
  const float* w3   = (const float*)d_in[5];
  const float* g1 = (const float*)d_in[6];
  const float* b1 = (const float*)d_in[7];
  const float* m1 = (const float*)d_in[8];
  const float* v1 = (const float*)d_in[9];
  const float* g2 = (const float*)d_in[10];
  const float* b2 = (const float*)d_in[11];
  const float* m2 = (const float*)d_in[12];
  const float* v2 = (const float*)d_in[13];
  const float* g3 = (const float*)d_in[14];
  const float* b3 = (const float*)d_in[15];
  const float* m3 = (const float*)d_in[16];
  const float* v3 = (const float*)d_in[17];
  char* ws = (char*)d_ws;

  hipMemsetAsync(d_ws, 0, 256, stream);  // zero amax slots every call
  prep_kernel<<<4368, 256, 0, stream>>>(w1, pegw, pegb, w2, w3,
                                        g1, b1, m1, v1, g2, b2, m2, v2,
                                        g3, b3, m3, v3, ws);
  amax_x_kernel<<<2048, 256, 0, stream>>>(x, (u32*)d_ws);
  conv1_kernel<<<512, 256, 0, stream>>>(x, ws);
  peg_kernel<<<1024, 256, 0, stream>>>(ws);
  conv2_kernel<<<256, 512, 0, stream>>>(ws);
  conv3_kernel<<<2048, 256, 0, stream>>>(x, (float*)d_out, ws);
}

// Round 9
// 241.364 us; speedup vs baseline: 1.1541x; 1.1541x over previous
//
#include <hip/hip_runtime.h>

typedef _Float16 f16;
typedef _Float16 f16x8 __attribute__((ext_vector_type(8)));
typedef float f32x4 __attribute__((ext_vector_type(4)));
typedef unsigned short u16;
typedef unsigned int u32;
typedef u32 u32x4 __attribute__((ext_vector_type(4)));

#define QMAX 32767.0f

// ---- workspace layout (bytes); total = 35,801,088 ----
#define WS_SLOTS    0u         // 4 x u32 amax slots: x, h1, h2, h3
#define WS_BN1_INV  256u       // 256 f32
#define WS_BN1_BETA 1280u
#define WS_BN2_INV  2304u
#define WS_BN2_BETA 3328u
#define WS_BN3_INV  4352u      // 1024 f32
#define WS_BN3_BETA 8448u
#define WS_PEG_B    12544u     // 256 f32
#define WS_PEGQ     13568u     // [9][256] f16
#define WS_W1Q      18432u     // [256 co][1024 ci] f16
#define WS_W3Q      542720u    // [1024 co][256 ci] f16
#define WS_W2Q      1067008u   // [9 tap][256 co][256 ci] f16
#define WS_H1T      2246656u   // [32768 p][256 c] f16 (reused as h3T)
#define WS_H2T      19023872u  // [32768 p][256 c] f16

__device__ __forceinline__ int badf(float f){  // Inf or NaN, fast-math-immune
  union { float f; u32 u; } c; c.f = f;
  return (c.u & 0x7f800000u) == 0x7f800000u;
}
// read amax slot -> guaranteed finite positive scale base
__device__ __forceinline__ float slot_amax(const u32* slots, int i){
  union { u32 u; float f; } c; c.u = slots[i];
  if ((c.u & 0x7f800000u) == 0x7f800000u) c.f = 1.0f;  // Inf/NaN -> 1.0
  float a = c.f;
  a = fminf(fmaxf(a, 1e-12f), 1e8f);
  return a;
}
// symmetric 16-bit fake-quant, Inf-safe (clamped to +-QMAX)
__device__ __forceinline__ float fq(float v, float is, float s){
  float t = v * is;
  t = fminf(fmaxf(t, -QMAX), QMAX);   // kills +-Inf; finite in, finite out
  return rintf(t) * s;
}
// DeepShift pow2 weight quant: sign(w)*2^clip(round(log2|w|), -14, 0)
__device__ __forceinline__ float qpow2(float w){
  float a = fabsf(w) + 1e-20f;
  float p = rintf(log2f(a));
  p = fminf(fmaxf(p, -14.0f), 0.0f);
  float m = exp2f(p);
  return (w > 0.0f) ? m : ((w < 0.0f) ? -m : 0.0f);
}
// LDS 16B-slot swizzle: uniform bank spread for [row][64B] tiles
#define SWZ(row, slot) ((((slot) ^ ((row) >> 1) ^ ((row) >> 3))) & 3)

__device__ __forceinline__ float wave_max(float v){
  #pragma unroll
  for (int off = 32; off > 0; off >>= 1) v = fmaxf(v, __shfl_xor(v, off));
  return v;
}
// block-level amax -> ONE device atomic per block
__device__ __forceinline__ void block_amax(float mx, u32* slot, float* red,
                                           int tid, int nw){
  mx = wave_max(mx);
  if ((tid & 63) == 0) red[tid >> 6] = mx;
  __syncthreads();
  if (tid == 0){
    float m = red[0];
    #pragma unroll
    for (int i = 1; i < 8; ++i) if (i < nw) m = fmaxf(m, red[i]);
    atomicMax(slot, __float_as_uint(m));
  }
}

// shared MFMA inner step (128x128 tile kernels): As at lds[0..8192), Bs at [8192..16384)
__device__ __forceinline__ void mfma_step(const char* lds, int wm, int wn,
                                          int lr, int lg, f32x4 acc[4][4]){
  f16x8 a[4], bb[4];
  #pragma unroll
  for (int mf = 0; mf < 4; ++mf){
    int row = (wm << 6) + (mf << 4) + lr;
    a[mf] = *(const f16x8*)(lds + (row << 6) + (SWZ(row, lg) << 4));
  }
  #pragma unroll
  for (int nf = 0; nf < 4; ++nf){
    int row = (wn << 6) + (nf << 4) + lr;
    bb[nf] = *(const f16x8*)(lds + 8192 + (row << 6) + (SWZ(row, lg) << 4));
  }
  #pragma unroll
  for (int mf = 0; mf < 4; ++mf)
    #pragma unroll
    for (int nf = 0; nf < 4; ++nf)
      acc[mf][nf] = __builtin_amdgcn_mfma_f32_16x16x32_f16(a[mf], bb[nf], acc[mf][nf], 0, 0, 0);
}

// ---- prep: quantize all weights to f16 pow2, precompute BN affine ----
__global__ __launch_bounds__(256) void prep_kernel(
    const float* __restrict__ w1, const float* __restrict__ pegw, const float* __restrict__ pegb,
    const float* __restrict__ w2, const float* __restrict__ w3,
    const float* g1, const float* b1, const float* m1, const float* v1,
    const float* g2, const float* b2, const float* m2, const float* v2,
    const float* g3, const float* b3, const float* m3, const float* v3,
    char* ws){
  int i = blockIdx.x * 256 + threadIdx.x;
  if (i < 262144){ ((f16*)(ws + WS_W1Q))[i] = (f16)qpow2(w1[i]); return; }
  i -= 262144;
  if (i < 589824){ // repack OIHW -> [tap][co][ci]
    int tap = i >> 16, rem = i & 65535;
    int co = rem >> 8, ci = rem & 255;
    ((f16*)(ws + WS_W2Q))[i] = (f16)qpow2(w2[(((co << 8) + ci) * 9) + tap]);
    return;
  }
  i -= 589824;
  if (i < 262144){ ((f16*)(ws + WS_W3Q))[i] = (f16)qpow2(w3[i]); return; }
  i -= 262144;
  if (i < 2304){ // [c][tap] -> [tap][c]
    int tap = i >> 8, c = i & 255;
    ((f16*)(ws + WS_PEGQ))[i] = (f16)qpow2(pegw[c * 9 + tap]);
    return;
  }
  i -= 2304;
  if (i < 256){ ((float*)(ws + WS_PEG_B))[i] = pegb[i]; return; }
  i -= 256;
  if (i < 256){
    float inv = g1[i] / sqrtf(v1[i] + 1e-5f);
    ((float*)(ws + WS_BN1_INV))[i] = inv;
    ((float*)(ws + WS_BN1_BETA))[i] = b1[i] - m1[i] * inv;
    return;
  }
  i -= 256;
  if (i < 256){
    float inv = g2[i] / sqrtf(v2[i] + 1e-5f);
    ((float*)(ws + WS_BN2_INV))[i] = inv;
    ((float*)(ws + WS_BN2_BETA))[i] = b2[i] - m2[i] * inv;
    return;
  }
  i -= 256;
  if (i < 1024){
    float inv = g3[i] / sqrtf(v3[i] + 1e-5f);
    ((float*)(ws + WS_BN3_INV))[i] = inv;
    ((float*)(ws + WS_BN3_BETA))[i] = b3[i] - m3[i] * inv;
  }
}

// ---- global amax(|x|) over 33.5M f32 ----
__global__ __launch_bounds__(256) void amax_x_kernel(const float* __restrict__ x, u32* slots){
  __shared__ float red[8];
  float m = 0.0f;
  int stride = gridDim.x * blockDim.x;
  for (int v = blockIdx.x * blockDim.x + threadIdx.x; v < 8388608; v += stride){
    f32x4 d = ((const f32x4*)x)[v];
    #pragma unroll
    for (int j = 0; j < 4; ++j) m = fmaxf(m, fabsf(d[j]));
  }
  block_amax(m, &slots[0], red, threadIdx.x, 4);
}

// ---- conv1: 1x1 1024->256. M=pixels(128-tile), N=co(128-tile), K=ci=1024. ----
__global__ __launch_bounds__(256) void conv1_kernel(const float* __restrict__ x, char* ws){
  __shared__ __align__(16) char lds[16384];
  __shared__ float red[8];
  const f16* w1q = (const f16*)(ws + WS_W1Q);
  f16* h1T = (f16*)(ws + WS_H1T);
  u32* slots = (u32*)(ws + WS_SLOTS);
  float am = slot_amax(slots, 0);
  float s0 = am / QMAX, is0 = QMAX / am;

  int tid = threadIdx.x, bid = blockIdx.x;
  int b = bid >> 4, m0 = ((bid >> 1) & 7) << 7, n0 = (bid & 1) << 7;
  int l = tid & 63, wid = tid >> 6, wm = wid >> 1, wn = wid & 1;
  int lr = l & 15, lg = l >> 4;
  f32x4 acc[4][4] = {};

  int pblk = tid & 15;   // 16 pixel-blocks of 8
  int cil  = tid >> 4;   // 16 ci rows per pass

  for (int ks = 0; ks < 32; ++ks){
    int k0 = ks << 5;
    // stage A: x[b][k0+ci][m0 + p] -> As[p][ci] (transpose + quant)
    #pragma unroll
    for (int i = 0; i < 2; ++i){
      int ci = cil + (i << 4);
      const float* src = x + (((size_t)(b << 10) + k0 + ci) << 10) + m0 + (pblk << 3);
      f32x4 d0 = *(const f32x4*)src;
      f32x4 d1 = *(const f32x4*)(src + 4);
      #pragma unroll
      for (int j = 0; j < 8; ++j){
        float xv = (j < 4) ? d0[j] : d1[j - 4];
        float q = fq(xv, is0, s0);
        int row = (pblk << 3) + j;
        *(f16*)(lds + (row << 6) + (SWZ(row, ci >> 3) << 4) + ((ci & 7) << 1)) = (f16)q;
      }
    }
    // stage B: w1q[n0+row][k0 + slot*8] copy
    #pragma unroll
    for (int i = 0; i < 2; ++i){
      int s = tid + (i << 8);
      int row = s >> 2, slot = s & 3;
      u32x4 d = *(const u32x4*)(w1q + ((size_t)(n0 + row) << 10) + k0 + (slot << 3));
      *(u32x4*)(lds + 8192 + (row << 6) + (SWZ(row, slot) << 4)) = d;
    }
    __syncthreads();
    mfma_step(lds, wm, wn, lr, lg, acc);
    __syncthreads();
  }

  float mx = 0.0f;
  #pragma unroll
  for (int mf = 0; mf < 4; ++mf){
    int p0 = m0 + (wm << 6) + (mf << 4) + (lg << 2);
    size_t base = ((size_t)(b << 10) + p0) << 8;
    #pragma unroll
    for (int nf = 0; nf < 4; ++nf){
      int co = n0 + (wn << 6) + (nf << 4) + lr;
      #pragma unroll
      for (int r = 0; r < 4; ++r){
        float f = acc[mf][nf][r];
        mx = fmaxf(mx, fabsf(f));
        h1T[base + ((size_t)r << 8) + co] = (f16)f;
      }
    }
  }
  block_amax(mx, &slots[1], red, tid, 4);
}

// ---- PEG: depthwise 3x3, block = one (batch,row), quantize once in LDS ----
__global__ __launch_bounds__(256) void peg_kernel(char* ws){
  __shared__ __align__(16) f16 tile[3][32][256];   // 48 KB
  __shared__ float red[8];
  const f16* h1T = (const f16*)(ws + WS_H1T);
  const f16* pegq = (const f16*)(ws + WS_PEGQ);
  const float* pb  = (const float*)(ws + WS_PEG_B);
  const float* inv1 = (const float*)(ws + WS_BN1_INV);
  const float* bt1  = (const float*)(ws + WS_BN1_BETA);
  f16* h2T = (f16*)(ws + WS_H2T);
  u32* slots = (u32*)(ws + WS_SLOTS);
  float am = slot_amax(slots, 1);
  float s1 = am / QMAX, is1 = QMAX / am;

  int tid = threadIdx.x;
  int b = blockIdx.x >> 5, h = blockIdx.x & 31;

  // stage rows h-1, h, h+1 (quantized); zeros outside image
  #pragma unroll
  for (int r = 0; r < 3; ++r){
    int hh = h + r - 1;
    #pragma unroll
    for (int i = 0; i < 4; ++i){
      int chunk = tid + (i << 8);          // 0..1023
      int px = chunk >> 5, cg = chunk & 31;
      u32x4 d = {0u, 0u, 0u, 0u};
      if ((u32)hh < 32u)
        d = *(const u32x4*)(h1T + (((size_t)(b << 10) + (hh << 5) + px) << 8) + (cg << 3));
      f16x8 hv = __builtin_bit_cast(f16x8, d);
      f16x8 qv;
      #pragma unroll
      for (int j = 0; j < 8; ++j) qv[j] = (f16)fq((float)hv[j], is1, s1);
      *(f16x8*)(&tile[r][px][cg << 3]) = qv;
    }
  }
  __syncthreads();

  int c0 = (tid & 31) << 3;   // 8 channels
  int q  = tid >> 5;          // pixel quad: px = 4q..4q+3
  float acc[4][8];
  #pragma unroll
  for (int i = 0; i < 4; ++i)
    #pragma unroll
    for (int j = 0; j < 8; ++j) acc[i][j] = pb[c0 + j];

  #pragma unroll
  for (int ky = 0; ky < 3; ++ky){
    #pragma unroll
    for (int kx = 0; kx < 3; ++kx){
      f16x8 wv = *(const f16x8*)(pegq + ((ky * 3 + kx) << 8) + c0);
      #pragma unroll
      for (int i = 0; i < 4; ++i){
        int ww = (q << 2) + i + kx - 1;
        if ((u32)ww < 32u){
          f16x8 v = *(const f16x8*)(&tile[ky][ww][c0]);
          #pragma unroll
          for (int j = 0; j < 8; ++j) acc[i][j] += (float)v[j] * (float)wv[j];
        }
      }
    }
  }

  f32x4 iv0 = *(const f32x4*)(inv1 + c0), iv1 = *(const f32x4*)(inv1 + c0 + 4);
  f32x4 bt0 = *(const f32x4*)(bt1 + c0),  bt1v = *(const f32x4*)(bt1 + c0 + 4);
  float mx = 0.0f;
  #pragma unroll
  for (int i = 0; i < 4; ++i){
    f16x8 o;
    #pragma unroll
    for (int j = 0; j < 8; ++j){
      float ivj = (j < 4) ? iv0[j] : iv1[j - 4];
      float btj = (j < 4) ? bt0[j] : bt1v[j - 4];
      float f = fmaxf(acc[i][j] * ivj + btj, 0.0f);
      mx = fmaxf(mx, f);
      o[j] = (f16)f;
    }
    int p = (h << 5) + (q << 2) + i;
    *(f16x8*)(h2T + (((size_t)(b << 10) + p) << 8) + c0) = o;
  }
  block_amax(mx, &slots[2], red, tid, 4);
}

// ---- conv2: 3x3 256->256. Block = 128 px x full 256 co, 8 waves; A staged once ----
__global__ __launch_bounds__(512) void conv2_kernel(char* ws){
  __shared__ __align__(16) char lds[104448 + 32768];  // A(6*34*512B) + B dbuf(2*16KB)
  __shared__ float red[8];
  const f16* h2T = (const f16*)(ws + WS_H2T);
  const f16* w2q = (const f16*)(ws + WS_W2Q);
  const float* inv2 = (const float*)(ws + WS_BN2_INV);
  const float* bt2  = (const float*)(ws + WS_BN2_BETA);
  f16* h3T = (f16*)(ws + WS_H1T);
  u32* slots = (u32*)(ws + WS_SLOTS);
  float am = slot_amax(slots, 2);
  float s2 = am / QMAX, is2 = QMAX / am;

  int tid = threadIdx.x, bid = blockIdx.x;
  int b = bid >> 3, mt = bid & 7;
  int h0 = mt << 2;             // first image row of tile
  int m0 = mt << 7;             // first pixel of tile
  int l = tid & 63, wid = tid >> 6, wm = wid >> 2, wn = wid & 3;
  int lr = l & 15, lg = l >> 4;
  char* A = lds;
  char* B0 = lds + 104448;
  char* B1 = lds + 104448 + 16384;

  // stage A once: tile[r][cc][ci], r=0..5 <-> image rows h0-1..h0+4,
  // cc=0..33 <-> cols -1..32 (zero halo). swizzled slot = slot ^ ((cc&7)<<2).
  for (int chunk = tid; chunk < 6528; chunk += 512){
    int r = chunk / 1088;                 // 1088 = 34*32
    int rem = chunk - r * 1088;
    int cc = rem >> 5, slot = rem & 31;
    int hh = h0 - 1 + r, wwp = cc - 1;
    u32x4 d = {0u, 0u, 0u, 0u};
    if ((u32)hh < 32u && (u32)wwp < 32u)
      d = *(const u32x4*)(h2T + (((size_t)(b << 10) + (hh << 5) + wwp) << 8) + (slot << 3));
    f16x8 hv = __builtin_bit_cast(f16x8, d);
    f16x8 qv;
    #pragma unroll
    for (int j = 0; j < 8; ++j) qv[j] = (f16)fq((float)hv[j], is2, s2);
    int sw = slot ^ ((cc & 7) << 2);
    *(f16x8*)(A + ((r * 34 + cc) << 9) + (sw << 4)) = qv;
  }
  // stage B for step 0 (tap 0, ks 0)
  #pragma unroll
  for (int i = 0; i < 2; ++i){
    int chunk = tid + (i << 9);
    int co = chunk >> 2, slot = chunk & 3;
    u32x4 d = *(const u32x4*)(w2q + (co << 8) + (slot << 3));
    *(u32x4*)(B0 + (co << 6) + (SWZ(co, slot) << 4)) = d;
  }
  __syncthreads();

  f32x4 acc[4][4] = {};
  for (int tap = 0; tap < 9; ++tap){
    int dy = tap / 3 - 1, dx = tap % 3 - 1;
    // hoist per-tap A fragment bases (each mf-frag's 16 lanes share one image row)
    int rowbase[4], key[4];
    #pragma unroll
    for (int mf = 0; mf < 4; ++mf){
      int p = (wm << 6) + (mf << 4) + lr;
      int rr = (p >> 5) + dy + 1;
      int cc = (p & 31) + dx + 1;
      rowbase[mf] = ((rr * 34 + cc) << 9) + (lg << 4);
      key[mf] = cc & 7;
    }
    #pragma unroll 2
    for (int ks = 0; ks < 8; ++ks){
      int t = (tap << 3) + ks;
      // early-issue next B tile global loads into regs
      u32x4 st[2];
      int have = (t < 71);
      int t1 = t + 1, wtap = t1 >> 3, wks = t1 & 7;
      const f16* srcb = w2q + wtap * 65536 + (wks << 5);
      if (have){
        #pragma unroll
        for (int i = 0; i < 2; ++i){
          int chunk = tid + (i << 9);
          int co = chunk >> 2, slot = chunk & 3;
          st[i] = *(const u32x4*)(srcb + (co << 8) + (slot << 3));
        }
      }
      // fragments
      const char* bs = (t & 1) ? B1 : B0;
      f16x8 a[4], bb[4];
      #pragma unroll
      for (int mf = 0; mf < 4; ++mf)
        a[mf] = *(const f16x8*)(A + rowbase[mf] + ((ks ^ key[mf]) << 6));
      #pragma unroll
      for (int nf = 0; nf < 4; ++nf){
        int row = (wn << 6) + (nf << 4) + lr;
        bb[nf] = *(const f16x8*)(bs + (row << 6) + (SWZ(row, lg) << 4));
      }
      #pragma unroll
      for (int mf = 0; mf < 4; ++mf)
        #pragma unroll
        for (int nf = 0; nf < 4; ++nf)
          acc[mf][nf] = __builtin_amdgcn_mfma_f32_16x16x32_f16(a[mf], bb[nf], acc[mf][nf], 0, 0, 0);
      // late write of staged B
      if (have){
        char* bd = (t1 & 1) ? B1 : B0;
        #pragma unroll
        for (int i = 0; i < 2; ++i){
          int chunk = tid + (i << 9);
          int co = chunk >> 2, slot = chunk & 3;
          *(u32x4*)(bd + (co << 6) + (SWZ(co, slot) << 4)) = st[i];
        }
      }
      __syncthreads();
    }
  }

  float mx = 0.0f;
  #pragma unroll
  for (int mf = 0; mf < 4; ++mf){
    int p0 = m0 + (wm << 6) + (mf << 4) + (lg << 2);
    size_t base = ((size_t)(b << 10) + p0) << 8;
    #pragma unroll
    for (int nf = 0; nf < 4; ++nf){
      int co = (wn << 6) + (nf << 4) + lr;
      float iv = inv2[co], bt = bt2[co];
      #pragma unroll
      for (int r = 0; r < 4; ++r){
        float f = fmaxf(acc[mf][nf][r] * iv + bt, 0.0f);
        mx = fmaxf(mx, f);
        h3T[base + ((size_t)r << 8) + co] = (f16)f;
      }
    }
  }
  block_amax(mx, &slots[3], red, tid, 8);
}

// ---- conv3: 1x1 256->1024. M=co, N=pixels (R6 structure, best measured).
// bn3 + residual + relu -> NCHW f32 via NON-TEMPORAL stores (out never
// re-read; keep L2/L3 capacity for the x-read stream). ----
__global__ __launch_bounds__(256) void conv3_kernel(const float* __restrict__ x,
                                                    float* __restrict__ out, char* ws){
  __shared__ __align__(16) char lds[16384];
  const f16* w3q = (const f16*)(ws + WS_W3Q);
  const f16* h3T = (const f16*)(ws + WS_H1T);
  const float* inv3 = (const float*)(ws + WS_BN3_INV);
  const float* bt3  = (const float*)(ws + WS_BN3_BETA);
  u32* slots = (u32*)(ws + WS_SLOTS);
  float am = slot_amax(slots, 3);
  float s3 = am / QMAX, is3 = QMAX / am;

  int tid = threadIdx.x, bid = blockIdx.x;
  int b = bid >> 6, m0 = ((bid >> 3) & 7) << 7, n0 = (bid & 7) << 7;
  int l = tid & 63, wid = tid >> 6, wm = wid >> 1, wn = wid & 1;
  int lr = l & 15, lg = l >> 4;
  f32x4 acc[4][4] = {};

  for (int ks = 0; ks < 8; ++ks){
    int k0 = ks << 5;
    // A = w3q[m0+row][k0..] copy
    #pragma unroll
    for (int i = 0; i < 2; ++i){
      int s = tid + (i << 8);
      int row = s >> 2, slot = s & 3;
      u32x4 d = *(const u32x4*)(w3q + ((size_t)(m0 + row) << 8) + k0 + (slot << 3));
      *(u32x4*)(lds + (row << 6) + (SWZ(row, slot) << 4)) = d;
    }
    // B = quant(h3T[n0+row][k0..])
    #pragma unroll
    for (int i = 0; i < 2; ++i){
      int s = tid + (i << 8);
      int row = s >> 2, slot = s & 3;
      u32x4 d = *(const u32x4*)(h3T + (((size_t)(b << 10) + n0 + row) << 8) + k0 + (slot << 3));
      f16x8 hv = __builtin_bit_cast(f16x8, d);
      f16x8 qv;
      #pragma unroll
      for (int j = 0; j < 8; ++j) qv[j] = (f16)fq((float)hv[j], is3, s3);
      *(f16x8*)(lds + 8192 + (row << 6) + (SWZ(row, slot) << 4)) = qv;
    }
    __syncthreads();
    mfma_step(lds, wm, wn, lr, lg, acc);
    __syncthreads();
  }

  #pragma unroll
  for (int mf = 0; mf < 4; ++mf){
    int co0 = m0 + (wm << 6) + (mf << 4) + (lg << 2);
    f32x4 iv = *(const f32x4*)(inv3 + co0);
    f32x4 bt = *(const f32x4*)(bt3 + co0);
    #pragma unroll
    for (int nf = 0; nf < 4; ++nf){
      int p = n0 + (wn << 6) + (nf << 4) + lr;
      #pragma unroll
      for (int r = 0; r < 4; ++r){
        size_t idx = (((size_t)(b << 10) + co0 + r) << 10) + p;
        float z = acc[mf][nf][r] * iv[r] + bt[r] + x[idx];
        float rr = fmaxf(z, 0.0f);
        if (badf(z)) rr = 512.0f;   // NaN/Inf beacon: visible in absmax
        __builtin_nontemporal_store(rr, &out[idx]);
      }
    }
  }
}

extern "C" void kernel_launch(void* const* d_in, const int* in_sizes, int n_in,
                              void* d_out, int out_size, void* d_ws, size_t ws_size,
                              hipStream_t stream){
  const float* x    = (const float*)d_in[0];
  const float* w1   = (const float*)d_in[1];
  const float* pegw = (const float*)d_in[2];
  const float* pegb = (const float*)d_in[3];
  const float* w2   = (const float*)d_in[4];
  const float* w3   = (const float*)d_in[5];
  const float* g1 = (const float*)d_in[6];
  const float* b1 = (const float*)d_in[7];
  const float* m1 = (const float*)d_in[8];
  const float* v1 = (const float*)d_in[9];
  const float* g2 = (const float*)d_in[10];
  const float* b2 = (const float*)d_in[11];
  const float* m2 = (const float*)d_in[12];
  const float* v2 = (const float*)d_in[13];
  const float* g3 = (const float*)d_in[14];
  const float* b3 = (const float*)d_in[15];
  const float* m3 = (const float*)d_in[16];
  const float* v3 = (const float*)d_in[17];
  char* ws = (char*)d_ws;

  hipMemsetAsync(d_ws, 0, 256, stream);  // zero amax slots every call
  prep_kernel<<<4368, 256, 0, stream>>>(w1, pegw, pegb, w2, w3,
                                        g1, b1, m1, v1, g2, b2, m2, v2,
                                        g3, b3, m3, v3, ws);
  amax_x_kernel<<<2048, 256, 0, stream>>>(x, (u32*)d_ws);
  conv1_kernel<<<512, 256, 0, stream>>>(x, ws);
  peg_kernel<<<1024, 256, 0, stream>>>(ws);
  conv2_kernel<<<256, 512, 0, stream>>>(ws);
  conv3_kernel<<<2048, 256, 0, stream>>>(x, (float*)d_out, ws);
}

// Round 10
// 235.520 us; speedup vs baseline: 1.1828x; 1.0248x over previous
//
#include <hip/hip_runtime.h>

typedef _Float16 f16;
typedef _Float16 f16x8 __attribute__((ext_vector_type(8)));
typedef float f32x4 __attribute__((ext_vector_type(4)));
typedef unsigned short u16;
typedef unsigned int u32;
typedef u32 u32x4 __attribute__((ext_vector_type(4)));

#define QMAX 32767.0f

// ---- workspace layout (bytes); total = 35,801,088 ----
#define WS_SLOTS    0u         // 4 x u32 amax slots: x, h1, h2, h3
#define WS_BN1_INV  256u       // 256 f32
#define WS_BN1_BETA 1280u
#define WS_BN2_INV  2304u
#define WS_BN2_BETA 3328u
#define WS_BN3_INV  4352u      // 1024 f32
#define WS_BN3_BETA 8448u
#define WS_PEG_B    12544u     // 256 f32
#define WS_PEGQ     13568u     // [9][256] f16
#define WS_W1Q      18432u     // [256 co][1024 ci] f16
#define WS_W3Q      542720u    // [1024 co][256 ci] f16
#define WS_W2Q      1067008u   // [9 tap][256 co][256 ci] f16
#define WS_H1T      2246656u   // [32768 p][256 c] f16 (reused as h3T)
#define WS_H2T      19023872u  // [32768 p][256 c] f16

__device__ __forceinline__ int badf(float f){  // Inf or NaN, fast-math-immune
  union { float f; u32 u; } c; c.f = f;
  return (c.u & 0x7f800000u) == 0x7f800000u;
}
// read amax slot -> guaranteed finite positive scale base
__device__ __forceinline__ float slot_amax(const u32* slots, int i){
  union { u32 u; float f; } c; c.u = slots[i];
  if ((c.u & 0x7f800000u) == 0x7f800000u) c.f = 1.0f;  // Inf/NaN -> 1.0
  float a = c.f;
  a = fminf(fmaxf(a, 1e-12f), 1e8f);
  return a;
}
// symmetric 16-bit fake-quant, Inf-safe (clamped to +-QMAX)
__device__ __forceinline__ float fq(float v, float is, float s){
  float t = v * is;
  t = fminf(fmaxf(t, -QMAX), QMAX);   // kills +-Inf; finite in, finite out
  return rintf(t) * s;
}
// DeepShift pow2 weight quant: sign(w)*2^clip(round(log2|w|), -14, 0)
__device__ __forceinline__ float qpow2(float w){
  float a = fabsf(w) + 1e-20f;
  float p = rintf(log2f(a));
  p = fminf(fmaxf(p, -14.0f), 0.0f);
  float m = exp2f(p);
  return (w > 0.0f) ? m : ((w < 0.0f) ? -m : 0.0f);
}
// LDS 16B-slot swizzle: uniform bank spread for [row][64B] tiles
#define SWZ(row, slot) ((((slot) ^ ((row) >> 1) ^ ((row) >> 3))) & 3)

__device__ __forceinline__ float wave_max(float v){
  #pragma unroll
  for (int off = 32; off > 0; off >>= 1) v = fmaxf(v, __shfl_xor(v, off));
  return v;
}
// block-level amax -> ONE device atomic per block
__device__ __forceinline__ void block_amax(float mx, u32* slot, float* red,
                                           int tid, int nw){
  mx = wave_max(mx);
  if ((tid & 63) == 0) red[tid >> 6] = mx;
  __syncthreads();
  if (tid == 0){
    float m = red[0];
    #pragma unroll
    for (int i = 1; i < 8; ++i) if (i < nw) m = fmaxf(m, red[i]);
    atomicMax(slot, __float_as_uint(m));
  }
}

// shared MFMA inner step (128x128 tile kernels): As at lds[0..8192), Bs at [8192..16384)
__device__ __forceinline__ void mfma_step(const char* lds, int wm, int wn,
                                          int lr, int lg, f32x4 acc[4][4]){
  f16x8 a[4], bb[4];
  #pragma unroll
  for (int mf = 0; mf < 4; ++mf){
    int row = (wm << 6) + (mf << 4) + lr;
    a[mf] = *(const f16x8*)(lds + (row << 6) + (SWZ(row, lg) << 4));
  }
  #pragma unroll
  for (int nf = 0; nf < 4; ++nf){
    int row = (wn << 6) + (nf << 4) + lr;
    bb[nf] = *(const f16x8*)(lds + 8192 + (row << 6) + (SWZ(row, lg) << 4));
  }
  #pragma unroll
  for (int mf = 0; mf < 4; ++mf)
    #pragma unroll
    for (int nf = 0; nf < 4; ++nf)
      acc[mf][nf] = __builtin_amdgcn_mfma_f32_16x16x32_f16(a[mf], bb[nf], acc[mf][nf], 0, 0, 0);
}

// ---- prep: quantize all weights to f16 pow2, precompute BN affine ----
__global__ __launch_bounds__(256) void prep_kernel(
    const float* __restrict__ w1, const float* __restrict__ pegw, const float* __restrict__ pegb,
    const float* __restrict__ w2, const float* __restrict__ w3,
    const float* g1, const float* b1, const float* m1, const float* v1,
    const float* g2, const float* b2, const float* m2, const float* v2,
    const float* g3, const float* b3, const float* m3, const float* v3,
    char* ws){
  int i = blockIdx.x * 256 + threadIdx.x;
  if (i < 262144){ ((f16*)(ws + WS_W1Q))[i] = (f16)qpow2(w1[i]); return; }
  i -= 262144;
  if (i < 589824){ // repack OIHW -> [tap][co][ci]
    int tap = i >> 16, rem = i & 65535;
    int co = rem >> 8, ci = rem & 255;
    ((f16*)(ws + WS_W2Q))[i] = (f16)qpow2(w2[(((co << 8) + ci) * 9) + tap]);
    return;
  }
  i -= 589824;
  if (i < 262144){ ((f16*)(ws + WS_W3Q))[i] = (f16)qpow2(w3[i]); return; }
  i -= 262144;
  if (i < 2304){ // [c][tap] -> [tap][c]
    int tap = i >> 8, c = i & 255;
    ((f16*)(ws + WS_PEGQ))[i] = (f16)qpow2(pegw[c * 9 + tap]);
    return;
  }
  i -= 2304;
  if (i < 256){ ((float*)(ws + WS_PEG_B))[i] = pegb[i]; return; }
  i -= 256;
  if (i < 256){
    float inv = g1[i] / sqrtf(v1[i] + 1e-5f);
    ((float*)(ws + WS_BN1_INV))[i] = inv;
    ((float*)(ws + WS_BN1_BETA))[i] = b1[i] - m1[i] * inv;
    return;
  }
  i -= 256;
  if (i < 256){
    float inv = g2[i] / sqrtf(v2[i] + 1e-5f);
    ((float*)(ws + WS_BN2_INV))[i] = inv;
    ((float*)(ws + WS_BN2_BETA))[i] = b2[i] - m2[i] * inv;
    return;
  }
  i -= 256;
  if (i < 1024){
    float inv = g3[i] / sqrtf(v3[i] + 1e-5f);
    ((float*)(ws + WS_BN3_INV))[i] = inv;
    ((float*)(ws + WS_BN3_BETA))[i] = b3[i] - m3[i] * inv;
  }
}

// ---- global amax(|x|) over 33.5M f32 ----
__global__ __launch_bounds__(256) void amax_x_kernel(const float* __restrict__ x, u32* slots){
  __shared__ float red[8];
  float m = 0.0f;
  int stride = gridDim.x * blockDim.x;
  for (int v = blockIdx.x * blockDim.x + threadIdx.x; v < 8388608; v += stride){
    f32x4 d = ((const f32x4*)x)[v];
    #pragma unroll
    for (int j = 0; j < 4; ++j) m = fmaxf(m, fabsf(d[j]));
  }
  block_amax(m, &slots[0], red, threadIdx.x, 4);
}

// ---- conv1: 1x1 1024->256. Block = 128 px x FULL 256 co, 8 waves (512 thr).
// x read exactly ONCE chip-wide (was 2x); w1q re-reads hit L2.
// A staged from NCHW f32 x with transpose+quant; K=1024 in 32 steps. ----
__global__ __launch_bounds__(512) void conv1_kernel(const float* __restrict__ x, char* ws){
  __shared__ __align__(16) char lds[24576];   // A 128x32 f16 (8KB) + B 256x32 f16 (16KB)
  __shared__ float red[8];
  const f16* w1q = (const f16*)(ws + WS_W1Q);
  f16* h1T = (f16*)(ws + WS_H1T);
  u32* slots = (u32*)(ws + WS_SLOTS);
  float am = slot_amax(slots, 0);
  float s0 = am / QMAX, is0 = QMAX / am;

  int tid = threadIdx.x, bid = blockIdx.x;
  int b = bid >> 3, m0 = (bid & 7) << 7;
  int l = tid & 63, wid = tid >> 6, wm = wid >> 2, wn = wid & 3;
  int lr = l & 15, lg = l >> 4;
  f32x4 acc[4][4] = {};

  int pblk = tid & 15;   // 16 pixel-blocks of 8
  int cil  = tid >> 4;   // 32 ci rows per pass

  for (int ks = 0; ks < 32; ++ks){
    int k0 = ks << 5;
    // stage A: x[b][k0+cil][m0 + p] -> As[p][ci] (transpose + quant), 1 pass
    {
      const float* src = x + (((size_t)(b << 10) + k0 + cil) << 10) + m0 + (pblk << 3);
      f32x4 d0 = *(const f32x4*)src;
      f32x4 d1 = *(const f32x4*)(src + 4);
      #pragma unroll
      for (int j = 0; j < 8; ++j){
        float xv = (j < 4) ? d0[j] : d1[j - 4];
        float q = fq(xv, is0, s0);
        int row = (pblk << 3) + j;
        *(f16*)(lds + (row << 6) + (SWZ(row, cil >> 3) << 4) + ((cil & 7) << 1)) = (f16)q;
      }
    }
    // stage B: w1q[row][k0 + slot*8], 256 rows x 64B
    #pragma unroll
    for (int i = 0; i < 2; ++i){
      int s = tid + (i << 9);
      int row = s >> 2, slot = s & 3;
      u32x4 d = *(const u32x4*)(w1q + ((size_t)row << 10) + k0 + (slot << 3));
      *(u32x4*)(lds + 8192 + (row << 6) + (SWZ(row, slot) << 4)) = d;
    }
    __syncthreads();
    // fragments: A rows 0..127 (wm in 0..1), B rows 0..255 (wn in 0..3)
    f16x8 a[4], bb[4];
    #pragma unroll
    for (int mf = 0; mf < 4; ++mf){
      int row = (wm << 6) + (mf << 4) + lr;
      a[mf] = *(const f16x8*)(lds + (row << 6) + (SWZ(row, lg) << 4));
    }
    #pragma unroll
    for (int nf = 0; nf < 4; ++nf){
      int row = (wn << 6) + (nf << 4) + lr;
      bb[nf] = *(const f16x8*)(lds + 8192 + (row << 6) + (SWZ(row, lg) << 4));
    }
    #pragma unroll
    for (int mf = 0; mf < 4; ++mf)
      #pragma unroll
      for (int nf = 0; nf < 4; ++nf)
        acc[mf][nf] = __builtin_amdgcn_mfma_f32_16x16x32_f16(a[mf], bb[nf], acc[mf][nf], 0, 0, 0);
    __syncthreads();
  }

  float mx = 0.0f;
  #pragma unroll
  for (int mf = 0; mf < 4; ++mf){
    int p0 = m0 + (wm << 6) + (mf << 4) + (lg << 2);
    size_t base = ((size_t)(b << 10) + p0) << 8;
    #pragma unroll
    for (int nf = 0; nf < 4; ++nf){
      int co = (wn << 6) + (nf << 4) + lr;
      #pragma unroll
      for (int r = 0; r < 4; ++r){
        float f = acc[mf][nf][r];
        mx = fmaxf(mx, fabsf(f));
        h1T[base + ((size_t)r << 8) + co] = (f16)f;
      }
    }
  }
  block_amax(mx, &slots[1], red, tid, 8);
}

// ---- PEG: depthwise 3x3, block = one (batch,row), quantize once in LDS ----
__global__ __launch_bounds__(256) void peg_kernel(char* ws){
  __shared__ __align__(16) f16 tile[3][32][256];   // 48 KB
  __shared__ float red[8];
  const f16* h1T = (const f16*)(ws + WS_H1T);
  const f16* pegq = (const f16*)(ws + WS_PEGQ);
  const float* pb  = (const float*)(ws + WS_PEG_B);
  const float* inv1 = (const float*)(ws + WS_BN1_INV);
  const float* bt1  = (const float*)(ws + WS_BN1_BETA);
  f16* h2T = (f16*)(ws + WS_H2T);
  u32* slots = (u32*)(ws + WS_SLOTS);
  float am = slot_amax(slots, 1);
  float s1 = am / QMAX, is1 = QMAX / am;

  int tid = threadIdx.x;
  int b = blockIdx.x >> 5, h = blockIdx.x & 31;

  // stage rows h-1, h, h+1 (quantized); zeros outside image
  #pragma unroll
  for (int r = 0; r < 3; ++r){
    int hh = h + r - 1;
    #pragma unroll
    for (int i = 0; i < 4; ++i){
      int chunk = tid + (i << 8);          // 0..1023
      int px = chunk >> 5, cg = chunk & 31;
      u32x4 d = {0u, 0u, 0u, 0u};
      if ((u32)hh < 32u)
        d = *(const u32x4*)(h1T + (((size_t)(b << 10) + (hh << 5) + px) << 8) + (cg << 3));
      f16x8 hv = __builtin_bit_cast(f16x8, d);
      f16x8 qv;
      #pragma unroll
      for (int j = 0; j < 8; ++j) qv[j] = (f16)fq((float)hv[j], is1, s1);
      *(f16x8*)(&tile[r][px][cg << 3]) = qv;
    }
  }
  __syncthreads();

  int c0 = (tid & 31) << 3;   // 8 channels
  int q  = tid >> 5;          // pixel quad: px = 4q..4q+3
  float acc[4][8];
  #pragma unroll
  for (int i = 0; i < 4; ++i)
    #pragma unroll
    for (int j = 0; j < 8; ++j) acc[i][j] = pb[c0 + j];

  #pragma unroll
  for (int ky = 0; ky < 3; ++ky){
    #pragma unroll
    for (int kx = 0; kx < 3; ++kx){
      f16x8 wv = *(const f16x8*)(pegq + ((ky * 3 + kx) << 8) + c0);
      #pragma unroll
      for (int i = 0; i < 4; ++i){
        int ww = (q << 2) + i + kx - 1;
        if ((u32)ww < 32u){
          f16x8 v = *(const f16x8*)(&tile[ky][ww][c0]);
          #pragma unroll
          for (int j = 0; j < 8; ++j) acc[i][j] += (float)v[j] * (float)wv[j];
        }
      }
    }
  }

  f32x4 iv0 = *(const f32x4*)(inv1 + c0), iv1 = *(const f32x4*)(inv1 + c0 + 4);
  f32x4 bt0 = *(const f32x4*)(bt1 + c0),  bt1v = *(const f32x4*)(bt1 + c0 + 4);
  float mx = 0.0f;
  #pragma unroll
  for (int i = 0; i < 4; ++i){
    f16x8 o;
    #pragma unroll
    for (int j = 0; j < 8; ++j){
      float ivj = (j < 4) ? iv0[j] : iv1[j - 4];
      float btj = (j < 4) ? bt0[j] : bt1v[j - 4];
      float f = fmaxf(acc[i][j] * ivj + btj, 0.0f);
      mx = fmaxf(mx, f);
      o[j] = (f16)f;
    }
    int p = (h << 5) + (q << 2) + i;
    *(f16x8*)(h2T + (((size_t)(b << 10) + p) << 8) + c0) = o;
  }
  block_amax(mx, &slots[2], red, tid, 4);
}

// ---- conv2: 3x3 256->256. Block = 128 px x full 256 co, 8 waves; A staged once ----
__global__ __launch_bounds__(512) void conv2_kernel(char* ws){
  __shared__ __align__(16) char lds[104448 + 32768];  // A(6*34*512B) + B dbuf(2*16KB)
  __shared__ float red[8];
  const f16* h2T = (const f16*)(ws + WS_H2T);
  const f16* w2q = (const f16*)(ws + WS_W2Q);
  const float* inv2 = (const float*)(ws + WS_BN2_INV);
  const float* bt2  = (const float*)(ws + WS_BN2_BETA);
  f16* h3T = (f16*)(ws + WS_H1T);
  u32* slots = (u32*)(ws + WS_SLOTS);
  float am = slot_amax(slots, 2);
  float s2 = am / QMAX, is2 = QMAX / am;

  int tid = threadIdx.x, bid = blockIdx.x;
  int b = bid >> 3, mt = bid & 7;
  int h0 = mt << 2;             // first image row of tile
  int m0 = mt << 7;             // first pixel of tile
  int l = tid & 63, wid = tid >> 6, wm = wid >> 2, wn = wid & 3;
  int lr = l & 15, lg = l >> 4;
  char* A = lds;
  char* B0 = lds + 104448;
  char* B1 = lds + 104448 + 16384;

  // stage A once: tile[r][cc][ci], r=0..5 <-> image rows h0-1..h0+4,
  // cc=0..33 <-> cols -1..32 (zero halo). swizzled slot = slot ^ ((cc&7)<<2).
  for (int chunk = tid; chunk < 6528; chunk += 512){
    int r = chunk / 1088;                 // 1088 = 34*32
    int rem = chunk - r * 1088;
    int cc = rem >> 5, slot = rem & 31;
    int hh = h0 - 1 + r, wwp = cc - 1;
    u32x4 d = {0u, 0u, 0u, 0u};
    if ((u32)hh < 32u && (u32)wwp < 32u)
      d = *(const u32x4*)(h2T + (((size_t)(b << 10) + (hh << 5) + wwp) << 8) + (slot << 3));
    f16x8 hv = __builtin_bit_cast(f16x8, d);
    f16x8 qv;
    #pragma unroll
    for (int j = 0; j < 8; ++j) qv[j] = (f16)fq((float)hv[j], is2, s2);
    int sw = slot ^ ((cc & 7) << 2);
    *(f16x8*)(A + ((r * 34 + cc) << 9) + (sw << 4)) = qv;
  }
  // stage B for step 0 (tap 0, ks 0)
  #pragma unroll
  for (int i = 0; i < 2; ++i){
    int chunk = tid + (i << 9);
    int co = chunk >> 2, slot = chunk & 3;
    u32x4 d = *(const u32x4*)(w2q + (co << 8) + (slot << 3));
    *(u32x4*)(B0 + (co << 6) + (SWZ(co, slot) << 4)) = d;
  }
  __syncthreads();

  f32x4 acc[4][4] = {};
  for (int tap = 0; tap < 9; ++tap){
    int dy = tap / 3 - 1, dx = tap % 3 - 1;
    // hoist per-tap A fragment bases (each mf-frag's 16 lanes share one image row)
    int rowbase[4], key[4];
    #pragma unroll
    for (int mf = 0; mf < 4; ++mf){
      int p = (wm << 6) + (mf << 4) + lr;
      int rr = (p >> 5) + dy + 1;
      int cc = (p & 31) + dx + 1;
      rowbase[mf] = ((rr * 34 + cc) << 9) + (lg << 4);
      key[mf] = cc & 7;
    }
    #pragma unroll 2
    for (int ks = 0; ks < 8; ++ks){
      int t = (tap << 3) + ks;
      // early-issue next B tile global loads into regs
      u32x4 st[2];
      int have = (t < 71);
      int t1 = t + 1, wtap = t1 >> 3, wks = t1 & 7;
      const f16* srcb = w2q + wtap * 65536 + (wks << 5);
      if (have){
        #pragma unroll
        for (int i = 0; i < 2; ++i){
          int chunk = tid + (i << 9);
          int co = chunk >> 2, slot = chunk & 3;
          st[i] = *(const u32x4*)(srcb + (co << 8) + (slot << 3));
        }
      }
      // fragments
      const char* bs = (t & 1) ? B1 : B0;
      f16x8 a[4], bb[4];
      #pragma unroll
      for (int mf = 0; mf < 4; ++mf)
        a[mf] = *(const f16x8*)(A + rowbase[mf] + ((ks ^ key[mf]) << 6));
      #pragma unroll
      for (int nf = 0; nf < 4; ++nf){
        int row = (wn << 6) + (nf << 4) + lr;
        bb[nf] = *(const f16x8*)(bs + (row << 6) + (SWZ(row, lg) << 4));
      }
      #pragma unroll
      for (int mf = 0; mf < 4; ++mf)
        #pragma unroll
        for (int nf = 0; nf < 4; ++nf)
          acc[mf][nf] = __builtin_amdgcn_mfma_f32_16x16x32_f16(a[mf], bb[nf], acc[mf][nf], 0, 0, 0);
      // late write of staged B
      if (have){
        char* bd = (t1 & 1) ? B1 : B0;
        #pragma unroll
        for (int i = 0; i < 2; ++i){
          int chunk = tid + (i << 9);
          int co = chunk >> 2, slot = chunk & 3;
          *(u32x4*)(bd + (co << 6) + (SWZ(co, slot) << 4)) = st[i];
        }
      }
      __syncthreads();
    }
  }

  float mx = 0.0f;
  #pragma unroll
  for (int mf = 0; mf < 4; ++mf){
    int p0 = m0 + (wm << 6) + (mf << 4) + (lg << 2);
    size_t base = ((size_t)(b << 10) + p0) << 8;
    #pragma unroll
    for (int nf = 0; nf < 4; ++nf){
      int co = (wn << 6) + (nf << 4) + lr;
      float iv = inv2[co], bt = bt2[co];
      #pragma unroll
      for (int r = 0; r < 4; ++r){
        float f = fmaxf(acc[mf][nf][r] * iv + bt, 0.0f);
        mx = fmaxf(mx, f);
        h3T[base + ((size_t)r << 8) + co] = (f16)f;
      }
    }
  }
  block_amax(mx, &slots[3], red, tid, 8);
}

// ---- conv3: 1x1 256->1024. M=co, N=pixels (R6 structure, best measured).
// bn3 + residual + relu -> NCHW f32 (plain stores; NT regressed). ----
__global__ __launch_bounds__(256) void conv3_kernel(const float* __restrict__ x,
                                                    float* __restrict__ out, char* ws){
  __shared__ __align__(16) char lds[16384];
  const f16* w3q = (const f16*)(ws + WS_W3Q);
  const f16* h3T = (const f16*)(ws + WS_H1T);
  const float* inv3 = (const float*)(ws + WS_BN3_INV);
  const float* bt3  = (const float*)(ws + WS_BN3_BETA);
  u32* slots = (u32*)(ws + WS_SLOTS);
  float am = slot_amax(slots, 3);
  float s3 = am / QMAX, is3 = QMAX / am;

  int tid = threadIdx.x, bid = blockIdx.x;
  int b = bid >> 6, m0 = ((bid >> 3) & 7) << 7, n0 = (bid & 7) << 7;
  int l = tid & 63, wid = tid >> 6, wm = wid >> 1, wn = wid & 1;
  int lr = l & 15, lg = l >> 4;
  f32x4 acc[4][4] = {};

  for (int ks = 0; ks < 8; ++ks){
    int k0 = ks << 5;
    // A = w3q[m0+row][k0..] copy
    #pragma unroll
    for (int i = 0; i < 2; ++i){
      int s = tid + (i << 8);
      int row = s >> 2, slot = s & 3;
      u32x4 d = *(const u32x4*)(w3q + ((size_t)(m0 + row) << 8) + k0 + (slot << 3));
      *(u32x4*)(lds + (row << 6) + (SWZ(row, slot) << 4)) = d;
    }
    // B = quant(h3T[n0+row][k0..])
    #pragma unroll
    for (int i = 0; i < 2; ++i){
      int s = tid + (i << 8);
      int row = s >> 2, slot = s & 3;
      u32x4 d = *(const u32x4*)(h3T + (((size_t)(b << 10) + n0 + row) << 8) + k0 + (slot << 3));
      f16x8 hv = __builtin_bit_cast(f16x8, d);
      f16x8 qv;
      #pragma unroll
      for (int j = 0; j < 8; ++j) qv[j] = (f16)fq((float)hv[j], is3, s3);
      *(f16x8*)(lds + 8192 + (row << 6) + (SWZ(row, slot) << 4)) = qv;
    }
    __syncthreads();
    mfma_step(lds, wm, wn, lr, lg, acc);
    __syncthreads();
  }

  #pragma unroll
  for (int mf = 0; mf < 4; ++mf){
    int co0 = m0 + (wm << 6) + (mf << 4) + (lg << 2);
    f32x4 iv = *(const f32x4*)(inv3 + co0);
    f32x4 bt = *(const f32x4*)(bt3 + co0);
    #pragma unroll
    for (int nf = 0; nf < 4; ++nf){
      int p = n0 + (wn << 6) + (nf << 4) + lr;
      #pragma unroll
      for (int r = 0; r < 4; ++r){
        size_t idx = (((size_t)(b << 10) + co0 + r) << 10) + p;
        float z = acc[mf][nf][r] * iv[r] + bt[r] + x[idx];
        float rr = fmaxf(z, 0.0f);
        if (badf(z)) rr = 512.0f;   // NaN/Inf beacon: visible in absmax
        out[idx] = rr;
      }
    }
  }
}

extern "C" void kernel_launch(void* const* d_in, const int* in_sizes, int n_in,
                              void* d_out, int out_size, void* d_ws, size_t ws_size,
                              hipStream_t stream){
  const float* x    = (const float*)d_in[0];
  const float* w1   = (const float*)d_in[1];
  const float* pegw = (const float*)d_in[2];
  const float* pegb = (const float*)d_in[3];
  const float* w2   = (const float*)d_in[4];
  const float* w3   = (const float*)d_in[5];
  const float* g1 = (const float*)d_in[6];
  const float* b1 = (const float*)d_in[7];
  const float* m1 = (const float*)d_in[8];
  const float* v1 = (const float*)d_in[9];
  const float* g2 = (const float*)d_in[10];
  const float* b2 = (const float*)d_in[11];
  const float* m2 = (const float*)d_in[12];
  const float* v2 = (const float*)d_in[13];
  const float* g3 = (const float*)d_in[14];
  const float* b3 = (const float*)d_in[15];
  const float* m3 = (const float*)d_in[16];
  const float* v3 = (const float*)d_in[17];
  char* ws = (char*)d_ws;

  hipMemsetAsync(d_ws, 0, 256, stream);  // zero amax slots every call
  prep_kernel<<<4368, 256, 0, stream>>>(w1, pegw, pegb, w2, w3,
                                        g1, b1, m1, v1, g2, b2, m2, v2,
                                        g3, b3, m3, v3, ws);
  amax_x_kernel<<<2048, 256, 0, stream>>>(x, (u32*)d_ws);
  conv1_kernel<<<256, 512, 0, stream>>>(x, ws);
  peg_kernel<<<1024, 256, 0, stream>>>(ws);
  conv2_kernel<<<256, 512, 0, stream>>>(ws);
  conv3_kernel<<<2048, 256, 0, stream>>>(x, (float*)d_out, ws);
}